// Round 2
// baseline (489.327 us; speedup 1.0000x reference)
//
#include <hip/hip_runtime.h>
#include <hip/hip_bf16.h>
#include <stdint.h>

#define B_ 2
#define S_ 2048
#define H_ 1024
#define F_ 4096
#define E_ 8
#define KTOP_ 2
#define NTOK (B_*S_)          // 4096
#define NPAIR (KTOP_*NTOK)    // 8192
#define NPAIR_PAD (NPAIR+256)

// ---- workspace layout (bytes) ----
static const size_t WS_XG   = 131072;
static const size_t SZ_XG   = (size_t)NPAIR_PAD * H_ * 2;
static const size_t WS_W1T  = WS_XG + SZ_XG;
static const size_t SZ_W1T  = (size_t)E_ * F_ * H_ * 2;
static const size_t WS_W2T  = WS_W1T + SZ_W1T;
static const size_t SZ_W2T  = (size_t)E_ * H_ * F_ * 2;
static const size_t WS_HBUF = WS_W2T + SZ_W2T;
static const size_t SZ_HBUF = (size_t)NPAIR_PAD * F_ * 2;
static const size_t WS_YBUF = WS_HBUF + SZ_HBUF;

typedef __attribute__((ext_vector_type(8))) short bf16x8;
typedef __attribute__((ext_vector_type(4))) float f32x4;

__device__ __forceinline__ unsigned short f2bf(float f) {
  unsigned int u = __float_as_uint(f);
  u += 0x7fffu + ((u >> 16) & 1u);
  return (unsigned short)(u >> 16);
}

__device__ __forceinline__ void load_lds16(const void* g, void* l) {
  __builtin_amdgcn_global_load_lds(
      (const __attribute__((address_space(1))) unsigned int*)g,
      (__attribute__((address_space(3))) unsigned int*)l, 16, 0, 0);
}

template <int N> __device__ __forceinline__ void waitcnt_vm() {
  asm volatile("s_waitcnt vmcnt(%0)" :: "n"(N) : "memory");
}

// meta ints: [0..7]=counts [8..15]=fill [16..24]=offs [25]=ntiles [32..71]=desc
__global__ void k_init(int* meta) {
  if (threadIdx.x < 32) meta[threadIdx.x] = 0;
}

__global__ void k_count(const int* __restrict__ sel, int* meta) {
  int i = blockIdx.x * 256 + threadIdx.x;
  if (i < NPAIR) atomicAdd(&meta[sel[i]], 1);
}

__global__ void k_scan(int* meta) {
  if (threadIdx.x == 0) {
    int acc = 0, t = 0;
    for (int e = 0; e < E_; e++) {
      meta[16 + e] = acc;
      int c = meta[e];
      for (int r0 = 0; r0 < c; r0 += 256) meta[32 + (t++)] = (e << 13) | r0;
      acc += c;
    }
    meta[24] = acc;
    meta[25] = t;
  }
}

__global__ void k_fill(const int* __restrict__ sel, const float* __restrict__ probs,
                       int* meta, int* __restrict__ tok, int* __restrict__ slot,
                       float* __restrict__ prob) {
  int i = blockIdx.x * 256 + threadIdx.x;
  if (i < NPAIR) {
    int e = sel[i];
    int pos = meta[16 + e] + atomicAdd(&meta[8 + e], 1);
    tok[pos]  = i & (NTOK - 1);
    slot[pos] = i;
    prob[pos] = probs[i];
  }
}

__global__ void k_gather(const float* __restrict__ x, const int* __restrict__ tok,
                         unsigned short* __restrict__ Xg) {
  int p = blockIdx.x, t = threadIdx.x;
  int token = tok[p];
  float4 v = ((const float4*)(x + (size_t)token * H_))[t];
  ushort4 o;
  o.x = f2bf(v.x); o.y = f2bf(v.y); o.z = f2bf(v.z); o.w = f2bf(v.w);
  ((ushort4*)(Xg + (size_t)p * H_))[t] = o;
}

// src [E][R][C] f32 -> dst [E][C][R] bf16.  64x64 tiles, coalesced ushort2 writes.
__global__ void k_transpose(const float* __restrict__ src, unsigned short* __restrict__ dst,
                            int R, int C) {
  __shared__ float tile[64][65];
  int e = blockIdx.z;
  size_t c0 = (size_t)blockIdx.x * 64, r0 = (size_t)blockIdx.y * 64;
  int t = threadIdx.x;
  int r = t >> 2, q = t & 3;
  const float4* s = (const float4*)(src + ((size_t)e * R + r0 + r) * C + c0 + q * 16);
  float4 v0 = s[0], v1 = s[1], v2 = s[2], v3 = s[3];
  float* tp = &tile[r][q * 16];
  tp[0]=v0.x; tp[1]=v0.y; tp[2]=v0.z; tp[3]=v0.w;
  tp[4]=v1.x; tp[5]=v1.y; tp[6]=v1.z; tp[7]=v1.w;
  tp[8]=v2.x; tp[9]=v2.y; tp[10]=v2.z; tp[11]=v2.w;
  tp[12]=v3.x; tp[13]=v3.y; tp[14]=v3.z; tp[15]=v3.w;
  __syncthreads();
  unsigned short* d = dst + ((size_t)e * C + c0) * R + r0;
#pragma unroll
  for (int i = 0; i < 8; i++) {
    int chunk = t + 256 * i;           // 0..2047
    int c = chunk >> 5, j = chunk & 31;
    ushort2 o;
    o.x = f2bf(tile[2 * j][c]);
    o.y = f2bf(tile[2 * j + 1][c]);
    *(ushort2*)(d + (size_t)c * R + 2 * j) = o;
  }
}

// ---------------- deep-pipelined grouped GEMM ----------------
// C[M=pairs(ragged), BN-tile] = A[M,K] * Wt[N,K]^T
// BM=256, BK=32 per slot, 4 slots, staged 3 tiles ahead, counted vmcnt.
// 512 threads = 8 waves (2 M x 4 N). Per-wave out: 128 x (NREP*16).
// swizzle: byte_col(bits5:4) ^= row(bits2:1)  (involution, both sides)

template <int MH, int NREP>
__device__ __forceinline__ void domfma(f32x4 (&acc)[8][NREP], const bf16x8 (&af)[4],
                                       const bf16x8 (&bfr)[NREP]) {
#pragma unroll
  for (int m = 0; m < 4; m++)
#pragma unroll
    for (int n = 0; n < NREP; n++)
      acc[MH * 4 + m][n] =
          __builtin_amdgcn_mfma_f32_16x16x32_bf16(af[m], bfr[n], acc[MH * 4 + m][n], 0, 0, 0);
}

template <int K, int NREP, int EP>
__global__ __launch_bounds__(512, 2) void k_gemm8(
    const short* __restrict__ Aall, const short* __restrict__ Wt,
    const float* __restrict__ bias, const int* __restrict__ meta,
    unsigned short* __restrict__ Hbuf, float* __restrict__ ybuf,
    const int* __restrict__ slotA, const float* __restrict__ prob) {
  constexpr int BN = NREP * 64;
  constexpr int NT = K / 32;
  constexpr int ASLOT = 256 * 64;           // bytes
  constexpr int BSLOT = BN * 64;
  constexpr int SLOT = ASLOT + BSLOT;
  constexpr int ALOADS = ASLOT / (512 * 16);  // 2
  constexpr int BLOADS = BSLOT / (512 * 16);  // 2 or 1
  constexpr int TLOADS = ALOADS + BLOADS;
  constexpr int NFULL = (EP == 0) ? F_ : H_;

  __shared__ __align__(1024) char lds[4 * SLOT];

  int tile = blockIdx.y;
  if (tile >= meta[25]) return;
  int d  = meta[32 + tile];
  int e  = d >> 13, r0 = d & 8191;
  int ne = meta[e];
  int p0 = meta[16 + e] + r0;
  int n0 = blockIdx.x * BN;
  const char* A0 = (const char*)(Aall + (size_t)p0 * K);
  const char* B0 = (const char*)(Wt + ((size_t)e * NFULL + n0) * K);

  int t = threadIdx.x, lane = t & 63;
  int wid = t >> 6, wr = wid >> 2, wc = wid & 3, g = lane >> 4, l15 = lane & 15;
  f32x4 acc[8][NREP] = {};

  auto stageA = [&](int kt) {
    char* dst = lds + (kt & 3) * SLOT;
    const char* src = A0 + kt * 64;
#pragma unroll
    for (int l = 0; l < ALOADS; l++) {
      int off = l * 8192 + t * 16;
      int row = off >> 6, inb = off & 63;
      int sw = inb ^ (((row >> 1) & 3) << 4);
      load_lds16(src + (size_t)row * (K * 2) + sw, dst + off);
    }
  };
  auto stageB = [&](int kt) {
    char* dst = lds + (kt & 3) * SLOT + ASLOT;
    const char* src = B0 + kt * 64;
#pragma unroll
    for (int l = 0; l < BLOADS; l++) {
      int off = l * 8192 + t * 16;
      int row = off >> 6, inb = off & 63;
      int sw = inb ^ (((row >> 1) & 3) << 4);
      load_lds16(src + (size_t)row * (K * 2) + sw, dst + off);
    }
  };

  bf16x8 af[4], bfr[NREP];
  auto readB = [&](int kt) {
    const char* base = lds + (kt & 3) * SLOT + ASLOT;
#pragma unroll
    for (int n = 0; n < NREP; n++) {
      int row = wc * (BN / 4) + n * 16 + l15;
      bfr[n] = *(const bf16x8*)(base + row * 64 + ((g * 16) ^ (((row >> 1) & 3) << 4)));
    }
  };

  // prologue: stage tiles 0,1,2
  stageA(0); stageB(0); stageA(1); stageB(1); stageA(2); stageB(2);
  waitcnt_vm<2 * TLOADS>();
  __builtin_amdgcn_s_barrier();
  __builtin_amdgcn_sched_barrier(0);

  int kt = 0;
  for (; kt < NT - 3; kt++) {
    const char* abase = lds + (kt & 3) * SLOT;
    // phase 0
    readB(kt);
#pragma unroll
    for (int m = 0; m < 4; m++) {
      int row = wr * 128 + m * 16 + l15;
      af[m] = *(const bf16x8*)(abase + row * 64 + ((g * 16) ^ (((row >> 1) & 3) << 4)));
    }
    stageA(kt + 3);
    __builtin_amdgcn_s_barrier();
    __builtin_amdgcn_s_setprio(1);
    domfma<0, NREP>(acc, af, bfr);
    __builtin_amdgcn_s_setprio(0);
    __builtin_amdgcn_s_barrier();
    __builtin_amdgcn_sched_barrier(0);
    // phase 1
#pragma unroll
    for (int m = 0; m < 4; m++) {
      int row = wr * 128 + (4 + m) * 16 + l15;
      af[m] = *(const bf16x8*)(abase + row * 64 + ((g * 16) ^ (((row >> 1) & 3) << 4)));
    }
    stageB(kt + 3);
    __builtin_amdgcn_s_barrier();
    __builtin_amdgcn_s_setprio(1);
    domfma<1, NREP>(acc, af, bfr);
    __builtin_amdgcn_s_setprio(0);
    waitcnt_vm<2 * TLOADS>();
    __builtin_amdgcn_s_barrier();
    __builtin_amdgcn_sched_barrier(0);
  }
  // tail: kt = NT-3, NT-2, NT-1 (no staging)
  for (; kt < NT; kt++) {
    const char* abase = lds + (kt & 3) * SLOT;
    readB(kt);
#pragma unroll
    for (int m = 0; m < 4; m++) {
      int row = wr * 128 + m * 16 + l15;
      af[m] = *(const bf16x8*)(abase + row * 64 + ((g * 16) ^ (((row >> 1) & 3) << 4)));
    }
    __builtin_amdgcn_s_barrier();
    __builtin_amdgcn_s_setprio(1);
    domfma<0, NREP>(acc, af, bfr);
    __builtin_amdgcn_s_setprio(0);
    __builtin_amdgcn_s_barrier();
    __builtin_amdgcn_sched_barrier(0);
#pragma unroll
    for (int m = 0; m < 4; m++) {
      int row = wr * 128 + (4 + m) * 16 + l15;
      af[m] = *(const bf16x8*)(abase + row * 64 + ((g * 16) ^ (((row >> 1) & 3) << 4)));
    }
    __builtin_amdgcn_s_barrier();
    __builtin_amdgcn_s_setprio(1);
    domfma<1, NREP>(acc, af, bfr);
    __builtin_amdgcn_s_setprio(0);
    if (kt == NT - 3) waitcnt_vm<TLOADS>();
    else if (kt == NT - 2) waitcnt_vm<0>();
    __builtin_amdgcn_s_barrier();
    __builtin_amdgcn_sched_barrier(0);
  }

  // epilogue
  if (EP == 0) {
#pragma unroll
    for (int n = 0; n < NREP; n++) {
      int col = n0 + wc * (BN / 4) + n * 16 + l15;
      float bv = bias[e * F_ + col];
#pragma unroll
      for (int m = 0; m < 8; m++) {
        int rbase = wr * 128 + m * 16 + g * 4;
#pragma unroll
        for (int r = 0; r < 4; r++) {
          int row = rbase + r;
          if (r0 + row < ne) {
            float x = acc[m][n][r] + bv;
            // gelu(x) = x*u/(1+u), u = exp2(x*(c1 + c2*x^2)), c = 2*log2e*0.7978845608*{1,0.044715}
            float x2 = x * x;
            float ttt = x * (2.302118f + 0.1029518f * x2);
            ttt = fminf(ttt, 60.f);
            float u = __builtin_amdgcn_exp2f(ttt);
            float rr = __frcp_rn(1.f + u);
            Hbuf[(size_t)(p0 + row) * F_ + col] = f2bf(x * u * rr);
          }
        }
      }
    }
  } else {
#pragma unroll
    for (int n = 0; n < NREP; n++) {
      int col = n0 + wc * (BN / 4) + n * 16 + l15;
      float bv = bias[e * H_ + col];
#pragma unroll
      for (int m = 0; m < 8; m++) {
        int rbase = wr * 128 + m * 16 + g * 4;
#pragma unroll
        for (int r = 0; r < 4; r++) {
          int row = rbase + r;
          if (r0 + row < ne) {
            int p = p0 + row;
            ybuf[(size_t)slotA[p] * H_ + col] = (acc[m][n][r] + bv) * prob[p];
          }
        }
      }
    }
  }
}

__global__ void k_combine(const float* __restrict__ yb, float* __restrict__ out) {
  size_t i = (size_t)blockIdx.x * 256 + threadIdx.x;
  float4 a = ((const float4*)yb)[i];
  float4 b = ((const float4*)(yb + (size_t)NTOK * H_))[i];
  float4 o;
  o.x = a.x + b.x; o.y = a.y + b.y; o.z = a.z + b.z; o.w = a.w + b.w;
  ((float4*)out)[i] = o;
}

extern "C" void kernel_launch(void* const* d_in, const int* in_sizes, int n_in,
                              void* d_out, int out_size, void* d_ws, size_t ws_size,
                              hipStream_t stream) {
  const float* x     = (const float*)d_in[0];
  const float* probs = (const float*)d_in[1];
  const int*   sel   = (const int*)d_in[2];
  const float* w1    = (const float*)d_in[3];
  const float* b1    = (const float*)d_in[4];
  const float* w2    = (const float*)d_in[5];
  const float* b2    = (const float*)d_in[6];
  float* out = (float*)d_out;

  char* W = (char*)d_ws;
  int*   meta = (int*)W;
  int*   tok  = (int*)(W + 4096);
  int*   slot = (int*)(W + 36864);
  float* prob = (float*)(W + 69632);
  unsigned short* Xg  = (unsigned short*)(W + WS_XG);
  short* w1t = (short*)(W + WS_W1T);
  short* w2t = (short*)(W + WS_W2T);
  unsigned short* Hb  = (unsigned short*)(W + WS_HBUF);
  float* yb  = (float*)(W + WS_YBUF);

  k_init<<<1, 256, 0, stream>>>(meta);
  k_count<<<NPAIR / 256, 256, 0, stream>>>(sel, meta);
  k_scan<<<1, 64, 0, stream>>>(meta);
  k_fill<<<NPAIR / 256, 256, 0, stream>>>(sel, probs, meta, tok, slot, prob);
  k_gather<<<NPAIR, 256, 0, stream>>>(x, tok, Xg);
  k_transpose<<<dim3(F_ / 64, H_ / 64, E_), 256, 0, stream>>>(w1, (unsigned short*)w1t, H_, F_);
  k_transpose<<<dim3(H_ / 64, F_ / 64, E_), 256, 0, stream>>>(w2, (unsigned short*)w2t, F_, H_);
  k_gemm8<H_, 4, 0><<<dim3(F_ / 256, 40), 512, 0, stream>>>(
      (const short*)Xg, w1t, b1, meta, Hb, yb, slot, prob);
  k_gemm8<F_, 2, 1><<<dim3(H_ / 128, 40), 512, 0, stream>>>(
      (const short*)Hb, w2t, b2, meta, Hb, yb, slot, prob);
  k_combine<<<(NTOK * H_ / 4) / 256, 256, 0, stream>>>(yb, out);
}

// Round 3
// 478.161 us; speedup vs baseline: 1.0234x; 1.0234x over previous
//
#include <hip/hip_runtime.h>
#include <hip/hip_bf16.h>
#include <stdint.h>

#define B_ 2
#define S_ 2048
#define H_ 1024
#define F_ 4096
#define E_ 8
#define KTOP_ 2
#define NTOK (B_*S_)          // 4096
#define NPAIR (KTOP_*NTOK)    // 8192
#define NPAIR_PAD (NPAIR+256)

// ---- workspace layout (bytes) ----
static const size_t WS_XG   = 131072;
static const size_t SZ_XG   = (size_t)NPAIR_PAD * H_ * 2;
static const size_t WS_W1T  = WS_XG + SZ_XG;
static const size_t SZ_W1T  = (size_t)E_ * F_ * H_ * 2;
static const size_t WS_W2T  = WS_W1T + SZ_W1T;
static const size_t SZ_W2T  = (size_t)E_ * H_ * F_ * 2;
static const size_t WS_HBUF = WS_W2T + SZ_W2T;
static const size_t SZ_HBUF = (size_t)NPAIR_PAD * F_ * 2;
static const size_t WS_YBUF = WS_HBUF + SZ_HBUF;

typedef __attribute__((ext_vector_type(8))) short bf16x8;
typedef __attribute__((ext_vector_type(4))) float f32x4;

__device__ __forceinline__ unsigned short f2bf(float f) {
  unsigned int u = __float_as_uint(f);
  u += 0x7fffu + ((u >> 16) & 1u);
  return (unsigned short)(u >> 16);
}

__device__ __forceinline__ void load_lds16(const void* g, void* l) {
  __builtin_amdgcn_global_load_lds(
      (const __attribute__((address_space(1))) unsigned int*)g,
      (__attribute__((address_space(3))) unsigned int*)l, 16, 0, 0);
}

// meta ints: [0..7]=counts [8..15]=fill [16..23]=offs [24]=total
// [25]=ntiles256 [26]=ntiles128 [32..71]=desc256 [72..151]=desc128
__global__ void k_init(int* meta) {
  if (threadIdx.x < 32) meta[threadIdx.x] = 0;
}

__global__ void k_count(const int* __restrict__ sel, int* meta) {
  int i = blockIdx.x * 256 + threadIdx.x;
  if (i < NPAIR) atomicAdd(&meta[sel[i]], 1);
}

__global__ void k_scan(int* meta) {
  if (threadIdx.x == 0) {
    int acc = 0, t256 = 0, t128 = 0;
    for (int e = 0; e < E_; e++) {
      meta[16 + e] = acc;
      int c = meta[e];
      for (int r0 = 0; r0 < c; r0 += 256) meta[32 + (t256++)] = (e << 13) | r0;
      for (int r0 = 0; r0 < c; r0 += 128) meta[72 + (t128++)] = (e << 13) | r0;
      acc += c;
    }
    meta[24] = acc;
    meta[25] = t256;
    meta[26] = t128;
  }
}

__global__ void k_fill(const int* __restrict__ sel, const float* __restrict__ probs,
                       int* meta, int* __restrict__ tok, int* __restrict__ slot,
                       float* __restrict__ prob) {
  int i = blockIdx.x * 256 + threadIdx.x;
  if (i < NPAIR) {
    int e = sel[i];
    int pos = meta[16 + e] + atomicAdd(&meta[8 + e], 1);
    tok[pos]  = i & (NTOK - 1);
    slot[pos] = i;
    prob[pos] = probs[i];
  }
}

__global__ void k_gather(const float* __restrict__ x, const int* __restrict__ tok,
                         unsigned short* __restrict__ Xg) {
  int p = blockIdx.x, t = threadIdx.x;
  int token = tok[p];
  float4 v = ((const float4*)(x + (size_t)token * H_))[t];
  ushort4 o;
  o.x = f2bf(v.x); o.y = f2bf(v.y); o.z = f2bf(v.z); o.w = f2bf(v.w);
  ((ushort4*)(Xg + (size_t)p * H_))[t] = o;
}

// src [E][R][C] f32 -> dst [E][C][R] bf16.  64x64 tiles, coalesced ushort2 writes.
__global__ void k_transpose(const float* __restrict__ src, unsigned short* __restrict__ dst,
                            int R, int C) {
  __shared__ float tile[64][65];
  int e = blockIdx.z;
  size_t c0 = (size_t)blockIdx.x * 64, r0 = (size_t)blockIdx.y * 64;
  int t = threadIdx.x;
  int r = t >> 2, q = t & 3;
  const float4* s = (const float4*)(src + ((size_t)e * R + r0 + r) * C + c0 + q * 16);
  float4 v0 = s[0], v1 = s[1], v2 = s[2], v3 = s[3];
  float* tp = &tile[r][q * 16];
  tp[0]=v0.x; tp[1]=v0.y; tp[2]=v0.z; tp[3]=v0.w;
  tp[4]=v1.x; tp[5]=v1.y; tp[6]=v1.z; tp[7]=v1.w;
  tp[8]=v2.x; tp[9]=v2.y; tp[10]=v2.z; tp[11]=v2.w;
  tp[12]=v3.x; tp[13]=v3.y; tp[14]=v3.z; tp[15]=v3.w;
  __syncthreads();
  unsigned short* d = dst + ((size_t)e * C + c0) * R + r0;
#pragma unroll
  for (int i = 0; i < 8; i++) {
    int chunk = t + 256 * i;           // 0..2047
    int c = chunk >> 5, j = chunk & 31;
    ushort2 o;
    o.x = f2bf(tile[2 * j][c]);
    o.y = f2bf(tile[2 * j + 1][c]);
    *(ushort2*)(d + (size_t)c * R + 2 * j) = o;
  }
}

// ---------------- 2-phase grouped GEMM (T3-minimum schedule) ----------------
// C[M=pairs(ragged), BN] = A[M,K] * Wt[N,K]^T, BK=64, double-buffered LDS.
// Per iter: issue stage(k+1) FIRST, then ds_read+MFMA of tile k, then ONE
// __syncthreads() (its vmcnt(0)+lgkmcnt(0) drain is the intended wait).
// 512 threads = 8 waves (2M x 4N). swizzle: byte[6:4] ^= row[2:0] both sides.

template <int K, int MREP, int NREP, int DBASE, int NIDX, int EP>
__global__ __launch_bounds__(512, EP == 0 ? 2 : 4) void k_gemm2p(
    const short* __restrict__ Aall, const short* __restrict__ Wt,
    const float* __restrict__ bias, const int* __restrict__ meta,
    unsigned short* __restrict__ Hbuf, float* __restrict__ ybuf,
    const int* __restrict__ slotA, const float* __restrict__ prob) {
  constexpr int BM = 2 * MREP * 16;
  constexpr int BN = 4 * NREP * 16;
  constexpr int NT = K / 64;
  constexpr int ABYTES = BM * 128;
  constexpr int BBYTES = BN * 128;
  constexpr int BUF = ABYTES + BBYTES;
  constexpr int LOADS = BUF / (512 * 16);
  constexpr int ALOADS = ABYTES / (512 * 16);
  constexpr int NFULL = (EP == 0) ? F_ : H_;

  __shared__ __align__(1024) char lds[2 * BUF];

  int tile = blockIdx.y;
  if (tile >= meta[NIDX]) return;
  int d  = meta[DBASE + tile];
  int e  = d >> 13, r0 = d & 8191;
  int ne = meta[e];
  int p0 = meta[16 + e] + r0;
  int n0 = blockIdx.x * BN;
  const char* A0 = (const char*)(Aall + (size_t)p0 * K);
  const char* B0 = (const char*)(Wt + ((size_t)e * NFULL + n0) * K);

  int t = threadIdx.x, lane = t & 63, wid = t >> 6;
  int wr = wid >> 2, wc = wid & 3, g = lane >> 4, l15 = lane & 15;
  f32x4 acc[MREP][NREP] = {};

  auto stage = [&](int kt, char* dst) {
    const char* sa = A0 + kt * 128;   // kt*64 elems * 2B
    const char* sb = B0 + kt * 128;
#pragma unroll
    for (int l = 0; l < LOADS; l++) {
      int off = l * 8192 + t * 16;
      if (l < ALOADS) {
        int row = off >> 7, inb = off & 127;
        load_lds16(sa + (size_t)row * (K * 2) + (inb ^ ((row & 7) << 4)), dst + off);
      } else {
        int o2 = off - ABYTES;
        int row = o2 >> 7, inb = o2 & 127;
        load_lds16(sb + (size_t)row * (K * 2) + (inb ^ ((row & 7) << 4)), dst + off);
      }
    }
  };

  stage(0, lds);
  __syncthreads();
  int cur = 0;
  for (int kt = 0; kt < NT; kt++) {
    const char* ab = lds + cur * BUF;
    const char* bb = ab + ABYTES;
    if (kt + 1 < NT) stage(kt + 1, lds + (cur ^ 1) * BUF);
    __builtin_amdgcn_s_setprio(1);
#pragma unroll
    for (int kk = 0; kk < 2; kk++) {
      bf16x8 af[MREP], bf[NREP];
#pragma unroll
      for (int m = 0; m < MREP; m++) {
        int row = wr * (MREP * 16) + m * 16 + l15;
        af[m] = *(const bf16x8*)(ab + row * 128 + ((kk * 64 + g * 16) ^ ((row & 7) << 4)));
      }
#pragma unroll
      for (int n = 0; n < NREP; n++) {
        int row = wc * (NREP * 16) + n * 16 + l15;
        bf[n] = *(const bf16x8*)(bb + row * 128 + ((kk * 64 + g * 16) ^ ((row & 7) << 4)));
      }
#pragma unroll
      for (int m = 0; m < MREP; m++)
#pragma unroll
        for (int n = 0; n < NREP; n++)
          acc[m][n] = __builtin_amdgcn_mfma_f32_16x16x32_bf16(af[m], bf[n], acc[m][n], 0, 0, 0);
    }
    __builtin_amdgcn_s_setprio(0);
    __syncthreads();
    cur ^= 1;
  }

  // epilogue
  if (EP == 0) {
#pragma unroll
    for (int n = 0; n < NREP; n++) {
      int col = n0 + wc * (NREP * 16) + n * 16 + l15;
      float bv = bias[e * F_ + col];
#pragma unroll
      for (int m = 0; m < MREP; m++) {
        int rbase = wr * (MREP * 16) + m * 16 + g * 4;
#pragma unroll
        for (int r = 0; r < 4; r++) {
          int row = rbase + r;
          if (r0 + row < ne) {
            float x = acc[m][n][r] + bv;
            // gelu(x) = x*u/(1+u), u = exp2(x*(c1 + c2*x^2))
            float x2 = x * x;
            float ttt = x * (2.302118f + 0.1029518f * x2);
            ttt = fminf(ttt, 60.f);
            float u = __builtin_amdgcn_exp2f(ttt);
            float rr = __frcp_rn(1.f + u);
            Hbuf[(size_t)(p0 + row) * F_ + col] = f2bf(x * u * rr);
          }
        }
      }
    }
  } else {
#pragma unroll
    for (int n = 0; n < NREP; n++) {
      int col = n0 + wc * (NREP * 16) + n * 16 + l15;
      float bv = bias[e * H_ + col];
#pragma unroll
      for (int m = 0; m < MREP; m++) {
        int rbase = wr * (MREP * 16) + m * 16 + g * 4;
#pragma unroll
        for (int r = 0; r < 4; r++) {
          int row = rbase + r;
          if (r0 + row < ne) {
            int p = p0 + row;
            ybuf[(size_t)slotA[p] * H_ + col] = (acc[m][n][r] + bv) * prob[p];
          }
        }
      }
    }
  }
}

__global__ void k_combine(const float* __restrict__ yb, float* __restrict__ out) {
  size_t i = (size_t)blockIdx.x * 256 + threadIdx.x;
  float4 a = ((const float4*)yb)[i];
  float4 b = ((const float4*)(yb + (size_t)NTOK * H_))[i];
  float4 o;
  o.x = a.x + b.x; o.y = a.y + b.y; o.z = a.z + b.z; o.w = a.w + b.w;
  ((float4*)out)[i] = o;
}

extern "C" void kernel_launch(void* const* d_in, const int* in_sizes, int n_in,
                              void* d_out, int out_size, void* d_ws, size_t ws_size,
                              hipStream_t stream) {
  const float* x     = (const float*)d_in[0];
  const float* probs = (const float*)d_in[1];
  const int*   sel   = (const int*)d_in[2];
  const float* w1    = (const float*)d_in[3];
  const float* b1    = (const float*)d_in[4];
  const float* w2    = (const float*)d_in[5];
  const float* b2    = (const float*)d_in[6];
  float* out = (float*)d_out;

  char* W = (char*)d_ws;
  int*   meta = (int*)W;
  int*   tok  = (int*)(W + 4096);
  int*   slot = (int*)(W + 36864);
  float* prob = (float*)(W + 69632);
  unsigned short* Xg  = (unsigned short*)(W + WS_XG);
  short* w1t = (short*)(W + WS_W1T);
  short* w2t = (short*)(W + WS_W2T);
  unsigned short* Hb  = (unsigned short*)(W + WS_HBUF);
  float* yb  = (float*)(W + WS_YBUF);

  k_init<<<1, 256, 0, stream>>>(meta);
  k_count<<<NPAIR / 256, 256, 0, stream>>>(sel, meta);
  k_scan<<<1, 64, 0, stream>>>(meta);
  k_fill<<<NPAIR / 256, 256, 0, stream>>>(sel, probs, meta, tok, slot, prob);
  k_gather<<<NPAIR, 256, 0, stream>>>(x, tok, Xg);
  k_transpose<<<dim3(F_ / 64, H_ / 64, E_), 256, 0, stream>>>(w1, (unsigned short*)w1t, H_, F_);
  k_transpose<<<dim3(H_ / 64, F_ / 64, E_), 256, 0, stream>>>(w2, (unsigned short*)w2t, F_, H_);
  // GEMM1: 256x256 tile, per-wave 128x64 (MREP=8, NREP=4), desc256 list
  k_gemm2p<H_, 8, 4, 32, 25, 0><<<dim3(F_ / 256, 40), 512, 0, stream>>>(
      (const short*)Xg, w1t, b1, meta, Hb, yb, slot, prob);
  // GEMM2: 128x128 tile, per-wave 64x32 (MREP=4, NREP=2), desc128 list, 2 blk/CU
  k_gemm2p<F_, 4, 2, 72, 26, 1><<<dim3(H_ / 128, 72), 512, 0, stream>>>(
      (const short*)Hb, w2t, b2, meta, Hb, yb, slot, prob);
  k_combine<<<(NTOK * H_ / 4) / 256, 256, 0, stream>>>(yb, out);
}

// Round 4
// 469.385 us; speedup vs baseline: 1.0425x; 1.0187x over previous
//
#include <hip/hip_runtime.h>
#include <hip/hip_bf16.h>
#include <stdint.h>

#define B_ 2
#define S_ 2048
#define H_ 1024
#define F_ 4096
#define E_ 8
#define KTOP_ 2
#define NTOK (B_*S_)          // 4096
#define NPAIR (KTOP_*NTOK)    // 8192
#define NPAIR_PAD (NPAIR+256)

// ---- workspace layout (bytes) ----
static const size_t WS_XG   = 131072;
static const size_t SZ_XG   = (size_t)NPAIR_PAD * H_ * 2;
static const size_t WS_W1T  = WS_XG + SZ_XG;
static const size_t SZ_W1T  = (size_t)E_ * F_ * H_ * 2;
static const size_t WS_W2T  = WS_W1T + SZ_W1T;
static const size_t SZ_W2T  = (size_t)E_ * H_ * F_ * 2;
static const size_t WS_HBUF = WS_W2T + SZ_W2T;
static const size_t SZ_HBUF = (size_t)NPAIR_PAD * F_ * 2;
static const size_t WS_YBUF = WS_HBUF + SZ_HBUF;

typedef __attribute__((ext_vector_type(8))) short bf16x8;
typedef __attribute__((ext_vector_type(4))) float f32x4;

__device__ __forceinline__ unsigned short f2bf(float f) {
  unsigned int u = __float_as_uint(f);
  u += 0x7fffu + ((u >> 16) & 1u);
  return (unsigned short)(u >> 16);
}

__device__ __forceinline__ void load_lds16(const void* g, void* l) {
  __builtin_amdgcn_global_load_lds(
      (const __attribute__((address_space(1))) unsigned int*)g,
      (__attribute__((address_space(3))) unsigned int*)l, 16, 0, 0);
}

// meta ints: [0..7]=counts [8..15]=fill [16..23]=offs [24]=total
// [25]=ntiles256 [26]=ntiles128 [32..71]=desc256 [72..151]=desc128
__global__ void k_init(int* meta) {
  if (threadIdx.x < 32) meta[threadIdx.x] = 0;
}

__global__ void k_count(const int* __restrict__ sel, int* meta) {
  int i = blockIdx.x * 256 + threadIdx.x;
  if (i < NPAIR) atomicAdd(&meta[sel[i]], 1);
}

__global__ void k_scan(int* meta) {
  if (threadIdx.x == 0) {
    int acc = 0, t256 = 0, t128 = 0;
    for (int e = 0; e < E_; e++) {
      meta[16 + e] = acc;
      int c = meta[e];
      for (int r0 = 0; r0 < c; r0 += 256) meta[32 + (t256++)] = (e << 13) | r0;
      for (int r0 = 0; r0 < c; r0 += 128) meta[72 + (t128++)] = (e << 13) | r0;
      acc += c;
    }
    meta[24] = acc;
    meta[25] = t256;
    meta[26] = t128;
  }
}

__global__ void k_fill(const int* __restrict__ sel, const float* __restrict__ probs,
                       int* meta, int* __restrict__ tok, int* __restrict__ slot,
                       float* __restrict__ prob) {
  int i = blockIdx.x * 256 + threadIdx.x;
  if (i < NPAIR) {
    int e = sel[i];
    int pos = meta[16 + e] + atomicAdd(&meta[8 + e], 1);
    tok[pos]  = i & (NTOK - 1);
    slot[pos] = i;
    prob[pos] = probs[i];
  }
}

__global__ void k_gather(const float* __restrict__ x, const int* __restrict__ tok,
                         unsigned short* __restrict__ Xg) {
  int p = blockIdx.x, t = threadIdx.x;
  int token = tok[p];
  float4 v = ((const float4*)(x + (size_t)token * H_))[t];
  ushort4 o;
  o.x = f2bf(v.x); o.y = f2bf(v.y); o.z = f2bf(v.z); o.w = f2bf(v.w);
  ((ushort4*)(Xg + (size_t)p * H_))[t] = o;
}

// src [E][R][C] f32 -> dst [E][C][R] bf16.  64x64 tiles, coalesced ushort2 writes.
__global__ void k_transpose(const float* __restrict__ src, unsigned short* __restrict__ dst,
                            int R, int C) {
  __shared__ float tile[64][65];
  int e = blockIdx.z;
  size_t c0 = (size_t)blockIdx.x * 64, r0 = (size_t)blockIdx.y * 64;
  int t = threadIdx.x;
  int r = t >> 2, q = t & 3;
  const float4* s = (const float4*)(src + ((size_t)e * R + r0 + r) * C + c0 + q * 16);
  float4 v0 = s[0], v1 = s[1], v2 = s[2], v3 = s[3];
  float* tp = &tile[r][q * 16];
  tp[0]=v0.x; tp[1]=v0.y; tp[2]=v0.z; tp[3]=v0.w;
  tp[4]=v1.x; tp[5]=v1.y; tp[6]=v1.z; tp[7]=v1.w;
  tp[8]=v2.x; tp[9]=v2.y; tp[10]=v2.z; tp[11]=v2.w;
  tp[12]=v3.x; tp[13]=v3.y; tp[14]=v3.z; tp[15]=v3.w;
  __syncthreads();
  unsigned short* d = dst + ((size_t)e * C + c0) * R + r0;
#pragma unroll
  for (int i = 0; i < 8; i++) {
    int chunk = t + 256 * i;           // 0..2047
    int c = chunk >> 5, j = chunk & 31;
    ushort2 o;
    o.x = f2bf(tile[2 * j][c]);
    o.y = f2bf(tile[2 * j + 1][c]);
    *(ushort2*)(d + (size_t)c * R + 2 * j) = o;
  }
}

__device__ __forceinline__ float gelu_f(float x) {
  float x2 = x * x;
  float ttt = x * (2.302118f + 0.1029518f * x2);
  ttt = fminf(ttt, 60.f);
  float u = __builtin_amdgcn_exp2f(ttt);
  float rr = __frcp_rn(1.f + u);
  return x * u * rr;
}

// ---------------- 8-phase counted-vmcnt grouped GEMM (GEMM1) ----------------
// BM=256, BN=256, BK=64/K-tile, 2 K-tiles per iter (dbuf0=even, dbuf1=odd).
// 512 threads = 8 waves (2M x 4N), per-wave C = 128x64 (acc[8][4]).
// Quadrant order per K-tile: (mh0,nh0)(mh0,nh1)(mh1,nh0)(mh1,nh1) so
// A-region last read = ph3, B-region = ph2 -> stage B' at ph3, A' at ph4.
// vmcnt(8) ONLY at ph4/ph8 (leaves 2 newest 4-load stages in flight).
template <int K>
__global__ __launch_bounds__(512, 2) void k_gemm8p(
    const short* __restrict__ Aall, const short* __restrict__ Wt,
    const float* __restrict__ bias, const int* __restrict__ meta,
    unsigned short* __restrict__ Hbuf) {
  constexpr int NI = K / 128;
  __shared__ __align__(1024) char lds[131072];
  int tile = blockIdx.y;
  if (tile >= meta[25]) return;
  int dsc = meta[32 + tile];
  int e = dsc >> 13, r0 = dsc & 8191;
  int ne = meta[e];
  int p0 = meta[16 + e] + r0;
  int n0 = blockIdx.x * 256;
  const char* A0 = (const char*)(Aall + (size_t)p0 * K);
  const char* B0 = (const char*)(Wt + ((size_t)e * F_ + n0) * K);
  int t = threadIdx.x, lane = t & 63, wid = t >> 6;
  int wr = wid >> 2, wc = wid & 3, g = lane >> 4, l15 = lane & 15;
  f32x4 acc[8][4] = {};

  auto stage = [&](int mat, int db, int kt) {
    const char* src = mat ? B0 : A0;
    char* dst = lds + db * 65536 + mat * 32768;
#pragma unroll
    for (int l = 0; l < 4; l++) {
      int off = l * 8192 + t * 16;
      int row = off >> 7, inb = off & 127;
      load_lds16(src + (size_t)row * (K * 2) + kt * 128 + (inb ^ ((row & 7) << 4)), dst + off);
    }
  };
  bf16x8 af[2][4], af2[2][4], bfv[2][2], bf2[2][2];
  auto readA = [&](int db, int mh, bf16x8 (&dv)[2][4]) {
#pragma unroll
    for (int kk = 0; kk < 2; kk++)
#pragma unroll
      for (int m = 0; m < 4; m++) {
        int row = wr * 128 + mh * 64 + m * 16 + l15;
        dv[kk][m] = *(const bf16x8*)(lds + db * 65536 + row * 128 +
                                     ((kk * 64 + g * 16) ^ ((row & 7) << 4)));
      }
  };
  auto readB = [&](int db, int nh, bf16x8 (&dv)[2][2]) {
#pragma unroll
    for (int kk = 0; kk < 2; kk++)
#pragma unroll
      for (int n = 0; n < 2; n++) {
        int row = wc * 64 + (nh * 2 + n) * 16 + l15;
        dv[kk][n] = *(const bf16x8*)(lds + db * 65536 + 32768 + row * 128 +
                                     ((kk * 64 + g * 16) ^ ((row & 7) << 4)));
      }
  };
  auto quad = [&](int mh, int nh, bf16x8 (&Av)[2][4], bf16x8 (&Bv)[2][2]) {
    __builtin_amdgcn_s_setprio(1);
#pragma unroll
    for (int kk = 0; kk < 2; kk++)
#pragma unroll
      for (int m = 0; m < 4; m++)
#pragma unroll
        for (int n = 0; n < 2; n++)
          acc[mh * 4 + m][nh * 2 + n] = __builtin_amdgcn_mfma_f32_16x16x32_bf16(
              Av[kk][m], Bv[kk][n], acc[mh * 4 + m][nh * 2 + n], 0, 0, 0);
    __builtin_amdgcn_s_setprio(0);
  };
  auto bar = []() { __builtin_amdgcn_s_barrier(); };
  auto lg0 = []() { asm volatile("s_waitcnt lgkmcnt(0)" ::: "memory"); };
  auto vm8 = []() { asm volatile("s_waitcnt vmcnt(8)" ::: "memory"); };
  auto vm0 = []() { asm volatile("s_waitcnt vmcnt(0)" ::: "memory"); };

  // prologue: dbuf0 <- ktile0 (B then A), dbuf1 <- ktile1 (B then A)
  stage(1, 0, 0); stage(0, 0, 0); stage(1, 1, 1); stage(0, 1, 1);
  vm8(); bar();

  for (int i = 0; i < NI - 1; i++) {
    int kn0 = 2 * i + 2, kn1 = 2 * i + 3;
    // ---- K-tile 2i (dbuf0) ----
    readA(0, 0, af); readB(0, 0, bfv);                 // ph1
    bar(); lg0(); quad(0, 0, af, bfv); bar();
    readB(0, 1, bf2);                                  // ph2
    bar(); lg0(); quad(0, 1, af, bf2); bar();
    readA(0, 1, af2); stage(1, 0, kn0);                // ph3: B' -> dbuf0
    bar(); lg0(); quad(1, 0, af2, bfv); bar();
    stage(0, 0, kn0); vm8();                           // ph4: A' -> dbuf0
    bar(); quad(1, 1, af2, bf2); bar();
    // ---- K-tile 2i+1 (dbuf1) ----
    readA(1, 0, af); readB(1, 0, bfv);                 // ph5
    bar(); lg0(); quad(0, 0, af, bfv); bar();
    readB(1, 1, bf2);                                  // ph6
    bar(); lg0(); quad(0, 1, af, bf2); bar();
    readA(1, 1, af2); stage(1, 1, kn1);                // ph7: B' -> dbuf1
    bar(); lg0(); quad(1, 0, af2, bfv); bar();
    stage(0, 1, kn1); vm8();                           // ph8: A' -> dbuf1
    bar(); quad(1, 1, af2, bf2); bar();
  }
  // ---- peeled last iter (no stages) ----
  readA(0, 0, af); readB(0, 0, bfv);
  bar(); lg0(); quad(0, 0, af, bfv); bar();
  readB(0, 1, bf2);
  bar(); lg0(); quad(0, 1, af, bf2); bar();
  readA(0, 1, af2);
  bar(); lg0(); quad(1, 0, af2, bfv); bar();
  vm0();                                               // dbuf1 content fully landed
  bar(); quad(1, 1, af2, bf2); bar();
  readA(1, 0, af); readB(1, 0, bfv);
  bar(); lg0(); quad(0, 0, af, bfv); bar();
  readB(1, 1, bf2);
  bar(); lg0(); quad(0, 1, af, bf2); bar();
  readA(1, 1, af2);
  bar(); lg0(); quad(1, 0, af2, bfv); bar();
  quad(1, 1, af2, bf2);

  // epilogue: GELU -> Hbuf (bf16)
#pragma unroll
  for (int n = 0; n < 4; n++) {
    int col = n0 + wc * 64 + n * 16 + l15;
    float bv = bias[e * F_ + col];
#pragma unroll
    for (int m = 0; m < 8; m++) {
      int rbase = wr * 128 + m * 16 + g * 4;
#pragma unroll
      for (int r = 0; r < 4; r++) {
        int row = rbase + r;
        if (r0 + row < ne) {
          float x = acc[m][n][r] + bv;
          Hbuf[(size_t)(p0 + row) * F_ + col] = f2bf(gelu_f(x));
        }
      }
    }
  }
}

// ---------------- 2-phase grouped GEMM (GEMM2, unchanged from round 3) ------
template <int K, int MREP, int NREP, int DBASE, int NIDX>
__global__ __launch_bounds__(512, 4) void k_gemm2p(
    const short* __restrict__ Aall, const short* __restrict__ Wt,
    const float* __restrict__ bias, const int* __restrict__ meta,
    float* __restrict__ ybuf, const int* __restrict__ slotA,
    const float* __restrict__ prob) {
  constexpr int BM = 2 * MREP * 16;
  constexpr int BN = 4 * NREP * 16;
  constexpr int NT = K / 64;
  constexpr int ABYTES = BM * 128;
  constexpr int BBYTES = BN * 128;
  constexpr int BUF = ABYTES + BBYTES;
  constexpr int LOADS = BUF / (512 * 16);
  constexpr int ALOADS = ABYTES / (512 * 16);

  __shared__ __align__(1024) char lds[2 * BUF];

  int tile = blockIdx.y;
  if (tile >= meta[NIDX]) return;
  int d = meta[DBASE + tile];
  int e = d >> 13, r0 = d & 8191;
  int ne = meta[e];
  int p0 = meta[16 + e] + r0;
  int n0 = blockIdx.x * BN;
  const char* A0 = (const char*)(Aall + (size_t)p0 * K);
  const char* B0 = (const char*)(Wt + ((size_t)e * H_ + n0) * K);

  int t = threadIdx.x, lane = t & 63, wid = t >> 6;
  int wr = wid >> 2, wc = wid & 3, g = lane >> 4, l15 = lane & 15;
  f32x4 acc[MREP][NREP] = {};

  auto stage = [&](int kt, char* dst) {
    const char* sa = A0 + kt * 128;
    const char* sb = B0 + kt * 128;
#pragma unroll
    for (int l = 0; l < LOADS; l++) {
      int off = l * 8192 + t * 16;
      if (l < ALOADS) {
        int row = off >> 7, inb = off & 127;
        load_lds16(sa + (size_t)row * (K * 2) + (inb ^ ((row & 7) << 4)), dst + off);
      } else {
        int o2 = off - ABYTES;
        int row = o2 >> 7, inb = o2 & 127;
        load_lds16(sb + (size_t)row * (K * 2) + (inb ^ ((row & 7) << 4)), dst + off);
      }
    }
  };

  stage(0, lds);
  __syncthreads();
  int cur = 0;
  for (int kt = 0; kt < NT; kt++) {
    const char* ab = lds + cur * BUF;
    const char* bb = ab + ABYTES;
    if (kt + 1 < NT) stage(kt + 1, lds + (cur ^ 1) * BUF);
    __builtin_amdgcn_s_setprio(1);
#pragma unroll
    for (int kk = 0; kk < 2; kk++) {
      bf16x8 afv[MREP], bfv[NREP];
#pragma unroll
      for (int m = 0; m < MREP; m++) {
        int row = wr * (MREP * 16) + m * 16 + l15;
        afv[m] = *(const bf16x8*)(ab + row * 128 + ((kk * 64 + g * 16) ^ ((row & 7) << 4)));
      }
#pragma unroll
      for (int n = 0; n < NREP; n++) {
        int row = wc * (NREP * 16) + n * 16 + l15;
        bfv[n] = *(const bf16x8*)(bb + row * 128 + ((kk * 64 + g * 16) ^ ((row & 7) << 4)));
      }
#pragma unroll
      for (int m = 0; m < MREP; m++)
#pragma unroll
        for (int n = 0; n < NREP; n++)
          acc[m][n] = __builtin_amdgcn_mfma_f32_16x16x32_bf16(afv[m], bfv[n], acc[m][n], 0, 0, 0);
    }
    __builtin_amdgcn_s_setprio(0);
    __syncthreads();
    cur ^= 1;
  }

#pragma unroll
  for (int n = 0; n < NREP; n++) {
    int col = n0 + wc * (NREP * 16) + n * 16 + l15;
    float bv = bias[e * H_ + col];
#pragma unroll
    for (int m = 0; m < MREP; m++) {
      int rbase = wr * (MREP * 16) + m * 16 + g * 4;
#pragma unroll
      for (int r = 0; r < 4; r++) {
        int row = rbase + r;
        if (r0 + row < ne) {
          int p = p0 + row;
          ybuf[(size_t)slotA[p] * H_ + col] = (acc[m][n][r] + bv) * prob[p];
        }
      }
    }
  }
}

__global__ void k_combine(const float* __restrict__ yb, float* __restrict__ out) {
  size_t i = (size_t)blockIdx.x * 256 + threadIdx.x;
  float4 a = ((const float4*)yb)[i];
  float4 b = ((const float4*)(yb + (size_t)NTOK * H_))[i];
  float4 o;
  o.x = a.x + b.x; o.y = a.y + b.y; o.z = a.z + b.z; o.w = a.w + b.w;
  ((float4*)out)[i] = o;
}

extern "C" void kernel_launch(void* const* d_in, const int* in_sizes, int n_in,
                              void* d_out, int out_size, void* d_ws, size_t ws_size,
                              hipStream_t stream) {
  const float* x     = (const float*)d_in[0];
  const float* probs = (const float*)d_in[1];
  const int*   sel   = (const int*)d_in[2];
  const float* w1    = (const float*)d_in[3];
  const float* b1    = (const float*)d_in[4];
  const float* w2    = (const float*)d_in[5];
  const float* b2    = (const float*)d_in[6];
  float* out = (float*)d_out;

  char* W = (char*)d_ws;
  int*   meta = (int*)W;
  int*   tok  = (int*)(W + 4096);
  int*   slot = (int*)(W + 36864);
  float* prob = (float*)(W + 69632);
  unsigned short* Xg  = (unsigned short*)(W + WS_XG);
  short* w1t = (short*)(W + WS_W1T);
  short* w2t = (short*)(W + WS_W2T);
  unsigned short* Hb  = (unsigned short*)(W + WS_HBUF);
  float* yb  = (float*)(W + WS_YBUF);

  k_init<<<1, 256, 0, stream>>>(meta);
  k_count<<<NPAIR / 256, 256, 0, stream>>>(sel, meta);
  k_scan<<<1, 64, 0, stream>>>(meta);
  k_fill<<<NPAIR / 256, 256, 0, stream>>>(sel, probs, meta, tok, slot, prob);
  k_gather<<<NPAIR, 256, 0, stream>>>(x, tok, Xg);
  k_transpose<<<dim3(F_ / 64, H_ / 64, E_), 256, 0, stream>>>(w1, (unsigned short*)w1t, H_, F_);
  k_transpose<<<dim3(H_ / 64, F_ / 64, E_), 256, 0, stream>>>(w2, (unsigned short*)w2t, F_, H_);
  // GEMM1: 256x256 8-phase counted-vmcnt, desc256 list
  k_gemm8p<H_><<<dim3(F_ / 256, 40), 512, 0, stream>>>(
      (const short*)Xg, w1t, b1, meta, Hb);
  // GEMM2: 128x128 2-phase, desc128 list, 2 blk/CU
  k_gemm2p<F_, 4, 2, 72, 26><<<dim3(H_ / 128, 72), 512, 0, stream>>>(
      (const short*)Hb, w2t, b2, meta, yb, slot, prob);
  k_combine<<<(NTOK * H_ / 4) / 256, 256, 0, stream>>>(yb, out);
}

// Round 5
// 454.576 us; speedup vs baseline: 1.0764x; 1.0326x over previous
//
#include <hip/hip_runtime.h>
#include <hip/hip_bf16.h>
#include <stdint.h>

#define B_ 2
#define S_ 2048
#define H_ 1024
#define F_ 4096
#define E_ 8
#define KTOP_ 2
#define NTOK (B_*S_)          // 4096
#define NPAIR (KTOP_*NTOK)    // 8192
#define NPAIR_PAD (NPAIR+256)

// ---- workspace layout (bytes) ----
static const size_t WS_XG   = 131072;
static const size_t SZ_XG   = (size_t)NPAIR_PAD * H_ * 2;
static const size_t WS_W1T  = WS_XG + SZ_XG;
static const size_t SZ_W1T  = (size_t)E_ * F_ * H_ * 2;
static const size_t WS_W2T  = WS_W1T + SZ_W1T;
static const size_t SZ_W2T  = (size_t)E_ * H_ * F_ * 2;
static const size_t WS_HBUF = WS_W2T + SZ_W2T;
static const size_t SZ_HBUF = (size_t)NPAIR_PAD * F_ * 2;
static const size_t WS_YBUF = WS_HBUF + SZ_HBUF;

typedef __attribute__((ext_vector_type(8))) short bf16x8;
typedef __attribute__((ext_vector_type(4))) float f32x4;

__device__ __forceinline__ unsigned short f2bf(float f) {
  unsigned int u = __float_as_uint(f);
  u += 0x7fffu + ((u >> 16) & 1u);
  return (unsigned short)(u >> 16);
}

__device__ __forceinline__ void load_lds16(const void* g, void* l) {
  __builtin_amdgcn_global_load_lds(
      (const __attribute__((address_space(1))) unsigned int*)g,
      (__attribute__((address_space(3))) unsigned int*)l, 16, 0, 0);
}

// meta ints: [0..7]=counts [8..15]=fill [16..23]=offs [24]=total
// [26]=ntiles128 [72..151]=desc128
__global__ void k_init(int* meta) {
  if (threadIdx.x < 32) meta[threadIdx.x] = 0;
}

__global__ void k_count(const int* __restrict__ sel, int* meta) {
  int i = blockIdx.x * 256 + threadIdx.x;
  if (i < NPAIR) atomicAdd(&meta[sel[i]], 1);
}

__global__ void k_scan(int* meta) {
  if (threadIdx.x == 0) {
    int acc = 0, t128 = 0;
    for (int e = 0; e < E_; e++) {
      meta[16 + e] = acc;
      int c = meta[e];
      for (int r0 = 0; r0 < c; r0 += 128) meta[72 + (t128++)] = (e << 13) | r0;
      acc += c;
    }
    meta[24] = acc;
    meta[26] = t128;
  }
}

__global__ void k_fill(const int* __restrict__ sel, const float* __restrict__ probs,
                       int* meta, int* __restrict__ tok, int* __restrict__ slot,
                       float* __restrict__ prob) {
  int i = blockIdx.x * 256 + threadIdx.x;
  if (i < NPAIR) {
    int e = sel[i];
    int pos = meta[16 + e] + atomicAdd(&meta[8 + e], 1);
    tok[pos]  = i & (NTOK - 1);
    slot[pos] = i;
    prob[pos] = probs[i];
  }
}

__global__ void k_gather(const float* __restrict__ x, const int* __restrict__ tok,
                         unsigned short* __restrict__ Xg) {
  int p = blockIdx.x, t = threadIdx.x;
  int token = tok[p];
  float4 v = ((const float4*)(x + (size_t)token * H_))[t];
  ushort4 o;
  o.x = f2bf(v.x); o.y = f2bf(v.y); o.z = f2bf(v.z); o.w = f2bf(v.w);
  ((ushort4*)(Xg + (size_t)p * H_))[t] = o;
}

// src [E][R][C] f32 -> dst [E][C][R] bf16.  64x64 tiles, coalesced ushort2 writes.
__global__ void k_transpose(const float* __restrict__ src, unsigned short* __restrict__ dst,
                            int R, int C) {
  __shared__ float tile[64][65];
  int e = blockIdx.z;
  size_t c0 = (size_t)blockIdx.x * 64, r0 = (size_t)blockIdx.y * 64;
  int t = threadIdx.x;
  int r = t >> 2, q = t & 3;
  const float4* s = (const float4*)(src + ((size_t)e * R + r0 + r) * C + c0 + q * 16);
  float4 v0 = s[0], v1 = s[1], v2 = s[2], v3 = s[3];
  float* tp = &tile[r][q * 16];
  tp[0]=v0.x; tp[1]=v0.y; tp[2]=v0.z; tp[3]=v0.w;
  tp[4]=v1.x; tp[5]=v1.y; tp[6]=v1.z; tp[7]=v1.w;
  tp[8]=v2.x; tp[9]=v2.y; tp[10]=v2.z; tp[11]=v2.w;
  tp[12]=v3.x; tp[13]=v3.y; tp[14]=v3.z; tp[15]=v3.w;
  __syncthreads();
  unsigned short* d = dst + ((size_t)e * C + c0) * R + r0;
#pragma unroll
  for (int i = 0; i < 8; i++) {
    int chunk = t + 256 * i;           // 0..2047
    int c = chunk >> 5, j = chunk & 31;
    ushort2 o;
    o.x = f2bf(tile[2 * j][c]);
    o.y = f2bf(tile[2 * j + 1][c]);
    *(ushort2*)(d + (size_t)c * R + 2 * j) = o;
  }
}

__device__ __forceinline__ float gelu_f(float x) {
  float x2 = x * x;
  float ttt = x * (2.302118f + 0.1029518f * x2);
  ttt = fminf(ttt, 60.f);
  float u = __builtin_amdgcn_exp2f(ttt);
  float rr = __frcp_rn(1.f + u);
  return x * u * rr;
}

// --------- m97-style grouped GEMM: 128x128 tile, BK=32, dbuf, 4 waves -------
// Loop: stage(k+1 -> buf^1); compute(k <- buf); __syncthreads(); (ONE drain
// per K-step, AFTER compute: loads fly under MFMA + cross-block TLP hides
// the drain). LDS 32 KB -> up to 5 blocks/CU; launch_bounds(256,4).
// Rows are 64 B; swizzle involution: off ^= ((off>>7)&7)<<4 applied to the
// per-lane GLOBAL source (LDS dest linear, rule 21) and to ds_read addrs.
// EP0: Hbuf = gelu(acc+b1) bf16.  EP1: ybuf[slot] = (acc+b2)*prob f32.
template <int K, int EP>
__global__ __launch_bounds__(256, 4) void k_gemmdb(
    const short* __restrict__ Aall, const short* __restrict__ Wt,
    const float* __restrict__ bias, const int* __restrict__ meta,
    unsigned short* __restrict__ Hbuf, float* __restrict__ ybuf,
    const int* __restrict__ slotA, const float* __restrict__ prob) {
  constexpr int NT = K / 32;
  constexpr int NFULL = (EP == 0) ? F_ : H_;
  __shared__ __align__(1024) char lds[2][16384];   // [buf][A 8K | B 8K]

  int tile = blockIdx.y;
  if (tile >= meta[26]) return;
  int dsc = meta[72 + tile];
  int e = dsc >> 13, r0 = dsc & 8191;
  int ne = meta[e];
  int p0 = meta[16 + e] + r0;
  int n0 = blockIdx.x * 128;
  const char* A0 = (const char*)(Aall + (size_t)p0 * K);
  const char* B0 = (const char*)(Wt + ((size_t)e * NFULL + n0) * K);

  int t = threadIdx.x, lane = t & 63, wid = t >> 6;
  int wr = wid >> 1, wc = wid & 1, g = lane >> 4, l15 = lane & 15;
  f32x4 acc[4][4] = {};

  auto stage = [&](int kt, char* dst) {
#pragma unroll
    for (int l = 0; l < 2; l++) {      // A: 2 chunks/thread
      int off = l * 4096 + t * 16;
      int o2 = off ^ (((off >> 7) & 7) << 4);
      int row = o2 >> 6, cb = o2 & 63;
      load_lds16(A0 + (size_t)row * (K * 2) + kt * 64 + cb, dst + off);
    }
#pragma unroll
    for (int l = 0; l < 2; l++) {      // B: 2 chunks/thread
      int off = l * 4096 + t * 16;
      int o2 = off ^ (((off >> 7) & 7) << 4);
      int row = o2 >> 6, cb = o2 & 63;
      load_lds16(B0 + (size_t)row * (K * 2) + kt * 64 + cb, dst + 8192 + off);
    }
  };

  auto compute = [&](const char* ab) {
    const char* bb = ab + 8192;
    bf16x8 af[4], bf[4];
#pragma unroll
    for (int m = 0; m < 4; m++) {
      int a = (wr * 64 + m * 16 + l15) * 64 + g * 16;
      af[m] = *(const bf16x8*)(ab + (a ^ (((a >> 7) & 7) << 4)));
    }
#pragma unroll
    for (int n = 0; n < 4; n++) {
      int b = (wc * 64 + n * 16 + l15) * 64 + g * 16;
      bf[n] = *(const bf16x8*)(bb + (b ^ (((b >> 7) & 7) << 4)));
    }
    __builtin_amdgcn_s_setprio(1);
#pragma unroll
    for (int m = 0; m < 4; m++)
#pragma unroll
      for (int n = 0; n < 4; n++)
        acc[m][n] = __builtin_amdgcn_mfma_f32_16x16x32_bf16(af[m], bf[n], acc[m][n], 0, 0, 0);
    __builtin_amdgcn_s_setprio(0);
  };

  stage(0, lds[0]);
  __syncthreads();
  int cur = 0;
  for (int kt = 0; kt < NT; kt++) {
    if (kt + 1 < NT) stage(kt + 1, lds[cur ^ 1]);
    compute(lds[cur]);
    __syncthreads();
    cur ^= 1;
  }

  if (EP == 0) {
#pragma unroll
    for (int n = 0; n < 4; n++) {
      int col = n0 + wc * 64 + n * 16 + l15;
      float bv = bias[e * F_ + col];
#pragma unroll
      for (int m = 0; m < 4; m++) {
        int rbase = wr * 64 + m * 16 + g * 4;
#pragma unroll
        for (int r = 0; r < 4; r++) {
          int row = rbase + r;
          if (r0 + row < ne) {
            float x = acc[m][n][r] + bv;
            Hbuf[(size_t)(p0 + row) * F_ + col] = f2bf(gelu_f(x));
          }
        }
      }
    }
  } else {
#pragma unroll
    for (int n = 0; n < 4; n++) {
      int col = n0 + wc * 64 + n * 16 + l15;
      float bv = bias[e * H_ + col];
#pragma unroll
      for (int m = 0; m < 4; m++) {
        int rbase = wr * 64 + m * 16 + g * 4;
#pragma unroll
        for (int r = 0; r < 4; r++) {
          int row = rbase + r;
          if (r0 + row < ne) {
            int p = p0 + row;
            ybuf[(size_t)slotA[p] * H_ + col] = (acc[m][n][r] + bv) * prob[p];
          }
        }
      }
    }
  }
}

__global__ void k_combine(const float* __restrict__ yb, float* __restrict__ out) {
  size_t i = (size_t)blockIdx.x * 256 + threadIdx.x;
  float4 a = ((const float4*)yb)[i];
  float4 b = ((const float4*)(yb + (size_t)NTOK * H_))[i];
  float4 o;
  o.x = a.x + b.x; o.y = a.y + b.y; o.z = a.z + b.z; o.w = a.w + b.w;
  ((float4*)out)[i] = o;
}

extern "C" void kernel_launch(void* const* d_in, const int* in_sizes, int n_in,
                              void* d_out, int out_size, void* d_ws, size_t ws_size,
                              hipStream_t stream) {
  const float* x     = (const float*)d_in[0];
  const float* probs = (const float*)d_in[1];
  const int*   sel   = (const int*)d_in[2];
  const float* w1    = (const float*)d_in[3];
  const float* b1    = (const float*)d_in[4];
  const float* w2    = (const float*)d_in[5];
  const float* b2    = (const float*)d_in[6];
  float* out = (float*)d_out;

  char* W = (char*)d_ws;
  int*   meta = (int*)W;
  int*   tok  = (int*)(W + 4096);
  int*   slot = (int*)(W + 36864);
  float* prob = (float*)(W + 69632);
  unsigned short* Xg  = (unsigned short*)(W + WS_XG);
  short* w1t = (short*)(W + WS_W1T);
  short* w2t = (short*)(W + WS_W2T);
  unsigned short* Hb  = (unsigned short*)(W + WS_HBUF);
  float* yb  = (float*)(W + WS_YBUF);

  k_init<<<1, 256, 0, stream>>>(meta);
  k_count<<<NPAIR / 256, 256, 0, stream>>>(sel, meta);
  k_scan<<<1, 64, 0, stream>>>(meta);
  k_fill<<<NPAIR / 256, 256, 0, stream>>>(sel, probs, meta, tok, slot, prob);
  k_gather<<<NPAIR, 256, 0, stream>>>(x, tok, Xg);
  k_transpose<<<dim3(F_ / 64, H_ / 64, E_), 256, 0, stream>>>(w1, (unsigned short*)w1t, H_, F_);
  k_transpose<<<dim3(H_ / 64, F_ / 64, E_), 256, 0, stream>>>(w2, (unsigned short*)w2t, F_, H_);
  // GEMM1: 128x128 BK=32 dbuf, grid 32 x 72
  k_gemmdb<H_, 0><<<dim3(F_ / 128, 72), 256, 0, stream>>>(
      (const short*)Xg, w1t, b1, meta, Hb, yb, slot, prob);
  // GEMM2: 128x128 BK=32 dbuf, grid 8 x 72
  k_gemmdb<F_, 1><<<dim3(H_ / 128, 72), 256, 0, stream>>>(
      (const short*)Hb, w2t, b2, meta, Hb, yb, slot, prob);
  k_combine<<<(NTOK * H_ / 4) / 256, 256, 0, stream>>>(yb, out);
}